// Round 9
// baseline (26.087 us; speedup 1.0000x reference)
//
#include <hip/hip_runtime.h>

#define BB 4096
#define SS 256
#define NOPS 7

// Split structure: the 29.4 MB trans_op passthrough goes on the driver copy
// path (hipMemcpyAsync D2D ~ fill-kernel BW, 6.7-6.9 TB/s measured on this
// chip); this kernel does only the logic + tv/td streams. The memcpy runs
// first and leaves op lines L2/L3-warm for the strided argmax read here.
__global__ __launch_bounds__(256) void arth_logic_kernel(
    const float* __restrict__ tv_in,
    const float* __restrict__ td_in,
    const float* __restrict__ op_in,
    const float* __restrict__ if_fin,
    const float* __restrict__ if_val,
    const int* __restrict__ start_pos_p,
    float* __restrict__ out_tv,
    float* __restrict__ out_td,
    float* __restrict__ out_iff,
    float* __restrict__ out_iv)
{
    __shared__ float s_td[SS];
    __shared__ unsigned char s_amax[SS];
    __shared__ unsigned long long sm_op[4];
    __shared__ unsigned long long sm_num[4];

    const int b = blockIdx.x;
    const int t = threadIdx.x;
    const size_t rbase = (size_t)b * SS;
    const size_t obase = (size_t)b * (SS * NOPS);

    // Block-uniform scalars (s_load).
    const int start_pos = *start_pos_p;
    const float fin_f = if_fin[b];
    const float iv0 = if_val[b];

    // ---- Loads: tv/td (coalesced dword) + thread t's 7 contiguous op
    // floats (consecutive threads tile the row fully -> line-efficient;
    // lines warm from the preceding D2D memcpy). Plain cached loads.
    const float tvv = tv_in[rbase + t];
    const float tdv = td_in[rbase + t];
    const float* p = op_in + obase + (size_t)t * NOPS;
    const float a0 = p[0], a1 = p[1], a2 = p[2], a3 = p[3];
    const float a4 = p[4], a5 = p[5], a6 = p[6];

    // Per-position argmax in registers (first-max-lowest-index = jnp.argmax).
    int am = 0; float best = a0;
    if (a1 > best) { best = a1; am = 1; }
    if (a2 > best) { best = a2; am = 2; }
    if (a3 > best) { best = a3; am = 3; }
    if (a4 > best) { best = a4; am = 4; }
    if (a5 > best) { best = a5; am = 5; }
    if (a6 > best) { best = a6; am = 6; }

    s_td[t] = tdv;
    s_amax[t] = (unsigned char)am;

    const bool validtok = (t >= start_pos) && (tvv > 0.5f);
    const bool is_num = validtok && (am == 0);
    const bool is_op = validtok && (am != 0);

    unsigned long long mo = __ballot(is_op);
    unsigned long long mn = __ballot(is_num);
    if ((t & 63) == 0) {
        sm_op[t >> 6] = mo;
        sm_num[t >> 6] = mn;
    }

    __syncthreads();   // single barrier: publishes s_td/s_amax/masks

    // All threads scan the 8 mask words (wave-uniform, broadcast LDS reads).
    unsigned long long w_op0 = sm_op[0], w_op1 = sm_op[1], w_op2 = sm_op[2], w_op3 = sm_op[3];
    unsigned long long m0 = sm_num[0], m1 = sm_num[1], m2 = sm_num[2], m3 = sm_num[3];

    // First valid op token j (or -1).
    int j = -1;
    if (w_op0)      j = __builtin_ctzll(w_op0);
    else if (w_op1) j = 64 + __builtin_ctzll(w_op1);
    else if (w_op2) j = 128 + __builtin_ctzll(w_op2);
    else if (w_op3) j = 192 + __builtin_ctzll(w_op3);

    // Restrict push masks to positions < j (straight-line, no loops).
    if (j >= 0) {
        const int jw = j >> 6, jb = j & 63;
        const unsigned long long low = (jb ? ((1ull << jb) - 1ull) : 0ull);
        m3 = (jw < 3) ? 0ull : ((jw == 3) ? (m3 & low) : m3);
        m2 = (jw < 2) ? 0ull : ((jw == 2) ? (m2 & low) : m2);
        m1 = (jw < 1) ? 0ull : ((jw == 1) ? (m1 & low) : m1);
        m0 = (jw == 0) ? (m0 & low) : m0;
    }

    // Top-two push positions: straight-line word scan.
    int i0 = -1, i1 = -1;
    {
        int w0 = -1;
        if (m3)      w0 = 3;
        else if (m2) w0 = 2;
        else if (m1) w0 = 1;
        else if (m0) w0 = 0;
        if (w0 >= 0) {
            unsigned long long mw = (w0 == 3) ? m3 : (w0 == 2) ? m2 : (w0 == 1) ? m1 : m0;
            const int bit = 63 - __builtin_clzll(mw);
            i0 = (w0 << 6) + bit;
            mw &= ~(1ull << bit);
            if (mw) i1 = (w0 << 6) + 63 - __builtin_clzll(mw);
            else {
                if (w0 >= 3 && m2)      i1 = 128 + 63 - __builtin_clzll(m2);
                else if (w0 >= 2 && m1) i1 = 64 + 63 - __builtin_clzll(m1);
                else if (w0 >= 1 && m0) i1 = 63 - __builtin_clzll(m0);
            }
        }
    }

    const bool finished = fin_f > 0.5f;
    const bool valid0 = iv0 > 0.5f;

    float otv = tvv, otd = tdv;
    float iff, ivout;
    if (finished) {
        iff = 1.0f;
        ivout = iv0;
    } else if (!valid0) {
        iff = 0.0f;
        ivout = 0.0f;
    } else if (j < 0) {
        ivout = 1.0f;
        iff = (i0 >= 0 && i1 < 0) ? 1.0f : 0.0f;
    } else if (i1 >= 0) {
        float h0 = s_td[i0];   // broadcast read
        float h1 = s_td[i1];   // broadcast read
        int op = s_amax[j];    // broadcast read
        float res;
        switch (op) {
            case 2: res = h1 + h0; break;
            case 3: res = h1 - h0; break;
            case 4: res = h1 * h0; break;
            case 5: res = h1 / (h0 + 1e-7f); break;
            case 6: res = powf(fmaxf(h1, 1e-7f), h0); break;
            default: res = 0.0f; break;   // op index 1 -> zero
        }
        if (t == i0) otd = res;
        if (t == i1 || t == j) otv = 0.0f;
        ivout = 1.0f;
        iff = 0.0f;
    } else {
        ivout = 0.0f;
        iff = 0.0f;
    }

    // Streaming writeback (nt stores: proven +0.7us in R3/R4 A/B).
    __builtin_nontemporal_store(otv, &out_tv[rbase + t]);
    __builtin_nontemporal_store(otd, &out_td[rbase + t]);
    if (t == 0) {
        __builtin_nontemporal_store(iff, &out_iff[b]);
        __builtin_nontemporal_store(ivout, &out_iv[b]);
    }
}

extern "C" void kernel_launch(void* const* d_in, const int* in_sizes, int n_in,
                              void* d_out, int out_size, void* d_ws, size_t ws_size,
                              hipStream_t stream) {
    const float* tv_in = (const float*)d_in[0];   // trans_valid (B,S)
    const float* td_in = (const float*)d_in[1];   // trans_dense (B,S)
    const float* op_in = (const float*)d_in[2];   // trans_op (B,S,7)
    const float* if_fin = (const float*)d_in[3];  // if_finished (B,)
    const float* if_val = (const float*)d_in[4];  // if_valid (B,)
    const int* start_pos = (const int*)d_in[5];   // scalar

    float* out = (float*)d_out;
    float* out_tv = out;                                    // B*S
    float* out_td = out + (size_t)BB * SS;                  // B*S
    float* out_op = out + (size_t)2 * BB * SS;              // B*S*7
    float* out_iff = out + (size_t)9 * BB * SS;             // B
    float* out_iv = out + (size_t)9 * BB * SS + BB;         // B

    // Bulk op passthrough on the driver copy path (captures as a graph
    // memcpy node; runs at ~6.7-6.9 TB/s per the fill-kernel evidence) and
    // warms L2/L3 for the logic kernel's op read right behind it.
    hipMemcpyAsync(out_op, op_in, (size_t)BB * SS * NOPS * sizeof(float),
                   hipMemcpyDeviceToDevice, stream);

    arth_logic_kernel<<<BB, SS, 0, stream>>>(tv_in, td_in, op_in, if_fin,
                                             if_val, start_pos, out_tv,
                                             out_td, out_iff, out_iv);
}

// Round 10
// 20.511 us; speedup vs baseline: 1.2719x; 1.2719x over previous
//
#include <hip/hip_runtime.h>

#define BB 4096
#define SS 256
#define NOPS 7
#define ROWS 2   // rows per block

typedef float f32x4 __attribute__((ext_vector_type(4)));

__device__ __forceinline__ void resolve_row(
    const unsigned long long* sm_op, const unsigned long long* sm_num,
    const float* s_td, const unsigned char* s_amax,
    float fin_f, float iv0, float tvv, float tdv, int t,
    float& otv, float& otd, float& iff, float& ivout)
{
    unsigned long long w_op0 = sm_op[0], w_op1 = sm_op[1], w_op2 = sm_op[2], w_op3 = sm_op[3];
    unsigned long long m0 = sm_num[0], m1 = sm_num[1], m2 = sm_num[2], m3 = sm_num[3];

    // First valid op token j (or -1).
    int j = -1;
    if (w_op0)      j = __builtin_ctzll(w_op0);
    else if (w_op1) j = 64 + __builtin_ctzll(w_op1);
    else if (w_op2) j = 128 + __builtin_ctzll(w_op2);
    else if (w_op3) j = 192 + __builtin_ctzll(w_op3);

    // Restrict push masks to positions < j (straight-line).
    if (j >= 0) {
        const int jw = j >> 6, jb = j & 63;
        const unsigned long long low = (jb ? ((1ull << jb) - 1ull) : 0ull);
        m3 = (jw < 3) ? 0ull : ((jw == 3) ? (m3 & low) : m3);
        m2 = (jw < 2) ? 0ull : ((jw == 2) ? (m2 & low) : m2);
        m1 = (jw < 1) ? 0ull : ((jw == 1) ? (m1 & low) : m1);
        m0 = (jw == 0) ? (m0 & low) : m0;
    }

    // Top-two push positions: straight-line word scan.
    int i0 = -1, i1 = -1;
    {
        int w0 = -1;
        if (m3)      w0 = 3;
        else if (m2) w0 = 2;
        else if (m1) w0 = 1;
        else if (m0) w0 = 0;
        if (w0 >= 0) {
            unsigned long long mw = (w0 == 3) ? m3 : (w0 == 2) ? m2 : (w0 == 1) ? m1 : m0;
            const int bit = 63 - __builtin_clzll(mw);
            i0 = (w0 << 6) + bit;
            mw &= ~(1ull << bit);
            if (mw) i1 = (w0 << 6) + 63 - __builtin_clzll(mw);
            else {
                if (w0 >= 3 && m2)      i1 = 128 + 63 - __builtin_clzll(m2);
                else if (w0 >= 2 && m1) i1 = 64 + 63 - __builtin_clzll(m1);
                else if (w0 >= 1 && m0) i1 = 63 - __builtin_clzll(m0);
            }
        }
    }

    const bool finished = fin_f > 0.5f;
    const bool valid0 = iv0 > 0.5f;

    otv = tvv; otd = tdv;
    if (finished) {
        iff = 1.0f; ivout = iv0;
    } else if (!valid0) {
        iff = 0.0f; ivout = 0.0f;
    } else if (j < 0) {
        ivout = 1.0f; iff = (i0 >= 0 && i1 < 0) ? 1.0f : 0.0f;
    } else if (i1 >= 0) {
        float h0 = s_td[i0];   // broadcast read
        float h1 = s_td[i1];   // broadcast read
        int op = s_amax[j];    // broadcast read
        float res;
        switch (op) {
            case 2: res = h1 + h0; break;
            case 3: res = h1 - h0; break;
            case 4: res = h1 * h0; break;
            case 5: res = h1 / (h0 + 1e-7f); break;
            case 6: res = powf(fmaxf(h1, 1e-7f), h0); break;
            default: res = 0.0f; break;   // op index 1 -> zero
        }
        if (t == i0) otd = res;
        if (t == i1 || t == j) otv = 0.0f;
        ivout = 1.0f; iff = 0.0f;
    } else {
        ivout = 0.0f; iff = 0.0f;
    }
}

__global__ __launch_bounds__(256) void arth_kernel(
    const float* __restrict__ tv_in,
    const float* __restrict__ td_in,
    const float* __restrict__ op_in,
    const float* __restrict__ if_fin,
    const float* __restrict__ if_val,
    const int* __restrict__ start_pos_p,
    float* __restrict__ out_tv,
    float* __restrict__ out_td,
    float* __restrict__ out_op,
    float* __restrict__ out_iff,
    float* __restrict__ out_iv)
{
    // Double-buffered tiny LDS: one barrier serves both rows.
    __shared__ float s_td[ROWS][SS];
    __shared__ unsigned char s_amax[ROWS][SS];
    __shared__ unsigned long long sm_op[ROWS][4];
    __shared__ unsigned long long sm_num[ROWS][4];

    const int t = threadIdx.x;
    const int r0 = blockIdx.x * ROWS;       // rows r0, r0+1 (adjacent -> contiguous op span)
    const size_t rb0 = (size_t)r0 * SS;
    const size_t rb1 = rb0 + SS;
    const size_t ob0 = (size_t)r0 * (SS * NOPS);
    const size_t ob1 = ob0 + SS * NOPS;

    const int start_pos = *start_pos_p;
    const float fin0 = if_fin[r0],  fin1 = if_fin[r0 + 1];
    const float ivv0 = if_val[r0],  ivv1 = if_val[r0 + 1];

    const f32x4* in4_0 = (const f32x4*)(op_in + ob0);
    const f32x4* in4_1 = (const f32x4*)(op_in + ob1);
    f32x4* o4_0 = (f32x4*)(out_op + ob0);
    f32x4* o4_1 = (f32x4*)(out_op + ob1);

    // ---- Issue BOTH rows' loads back-to-back (R5 order per row:
    // copy x4 loads first, then the L1-hot scalar argmax re-read). ----
    f32x4 v0_0 = in4_0[t];
    f32x4 v1_0; if (t < 192) v1_0 = in4_0[256 + t];
    f32x4 v0_1 = in4_1[t];
    f32x4 v1_1; if (t < 192) v1_1 = in4_1[256 + t];

    const float* p0 = op_in + ob0 + (size_t)t * NOPS;
    const float a0 = p0[0], a1 = p0[1], a2 = p0[2], a3 = p0[3];
    const float a4 = p0[4], a5 = p0[5], a6 = p0[6];
    const float* p1 = op_in + ob1 + (size_t)t * NOPS;
    const float c0 = p1[0], c1 = p1[1], c2 = p1[2], c3 = p1[3];
    const float c4 = p1[4], c5 = p1[5], c6 = p1[6];

    const float tvv0 = tv_in[rb0 + t], tdv0 = td_in[rb0 + t];
    const float tvv1 = tv_in[rb1 + t], tdv1 = td_in[rb1 + t];

    // ---- Row 0 pre-barrier: argmax, publish, ballots. ----
    int am0 = 0; float best0 = a0;
    if (a1 > best0) { best0 = a1; am0 = 1; }
    if (a2 > best0) { best0 = a2; am0 = 2; }
    if (a3 > best0) { best0 = a3; am0 = 3; }
    if (a4 > best0) { best0 = a4; am0 = 4; }
    if (a5 > best0) { best0 = a5; am0 = 5; }
    if (a6 > best0) { best0 = a6; am0 = 6; }
    s_td[0][t] = tdv0;
    s_amax[0][t] = (unsigned char)am0;
    {
        const bool vt = (t >= start_pos) && (tvv0 > 0.5f);
        unsigned long long mo = __ballot(vt && (am0 != 0));
        unsigned long long mn = __ballot(vt && (am0 == 0));
        if ((t & 63) == 0) { sm_op[0][t >> 6] = mo; sm_num[0][t >> 6] = mn; }
    }

    // ---- Row 1 pre-barrier. ----
    int am1 = 0; float best1 = c0;
    if (c1 > best1) { best1 = c1; am1 = 1; }
    if (c2 > best1) { best1 = c2; am1 = 2; }
    if (c3 > best1) { best1 = c3; am1 = 3; }
    if (c4 > best1) { best1 = c4; am1 = 4; }
    if (c5 > best1) { best1 = c5; am1 = 5; }
    if (c6 > best1) { best1 = c6; am1 = 6; }
    s_td[1][t] = tdv1;
    s_amax[1][t] = (unsigned char)am1;
    {
        const bool vt = (t >= start_pos) && (tvv1 > 0.5f);
        unsigned long long mo = __ballot(vt && (am1 != 0));
        unsigned long long mn = __ballot(vt && (am1 == 0));
        if ((t & 63) == 0) { sm_op[1][t >> 6] = mo; sm_num[1][t >> 6] = mn; }
    }

    // Streaming copy stores for both rows (nt proven +0.7us), pre-barrier.
    __builtin_nontemporal_store(v0_0, &o4_0[t]);
    if (t < 192) __builtin_nontemporal_store(v1_0, &o4_0[256 + t]);
    __builtin_nontemporal_store(v0_1, &o4_1[t]);
    if (t < 192) __builtin_nontemporal_store(v1_1, &o4_1[256 + t]);

    __syncthreads();   // ONE barrier for both rows

    // ---- Resolve + writeback, row 0 then row 1. ----
    float otv, otd, iff, ivo;
    resolve_row(sm_op[0], sm_num[0], s_td[0], s_amax[0],
                fin0, ivv0, tvv0, tdv0, t, otv, otd, iff, ivo);
    __builtin_nontemporal_store(otv, &out_tv[rb0 + t]);
    __builtin_nontemporal_store(otd, &out_td[rb0 + t]);
    if (t == 0) {
        __builtin_nontemporal_store(iff, &out_iff[r0]);
        __builtin_nontemporal_store(ivo, &out_iv[r0]);
    }

    resolve_row(sm_op[1], sm_num[1], s_td[1], s_amax[1],
                fin1, ivv1, tvv1, tdv1, t, otv, otd, iff, ivo);
    __builtin_nontemporal_store(otv, &out_tv[rb1 + t]);
    __builtin_nontemporal_store(otd, &out_td[rb1 + t]);
    if (t == 0) {
        __builtin_nontemporal_store(iff, &out_iff[r0 + 1]);
        __builtin_nontemporal_store(ivo, &out_iv[r0 + 1]);
    }
}

extern "C" void kernel_launch(void* const* d_in, const int* in_sizes, int n_in,
                              void* d_out, int out_size, void* d_ws, size_t ws_size,
                              hipStream_t stream) {
    const float* tv_in = (const float*)d_in[0];   // trans_valid (B,S)
    const float* td_in = (const float*)d_in[1];   // trans_dense (B,S)
    const float* op_in = (const float*)d_in[2];   // trans_op (B,S,7)
    const float* if_fin = (const float*)d_in[3];  // if_finished (B,)
    const float* if_val = (const float*)d_in[4];  // if_valid (B,)
    const int* start_pos = (const int*)d_in[5];   // scalar

    float* out = (float*)d_out;
    float* out_tv = out;                                    // B*S
    float* out_td = out + (size_t)BB * SS;                  // B*S
    float* out_op = out + (size_t)2 * BB * SS;              // B*S*7
    float* out_iff = out + (size_t)9 * BB * SS;             // B
    float* out_iv = out + (size_t)9 * BB * SS + BB;         // B

    arth_kernel<<<BB / ROWS, SS, 0, stream>>>(tv_in, td_in, op_in, if_fin,
                                              if_val, start_pos, out_tv,
                                              out_td, out_op, out_iff, out_iv);
}

// Round 11
// 16.658 us; speedup vs baseline: 1.5661x; 1.2313x over previous
//
#include <hip/hip_runtime.h>

#define BB 4096
#define SS 256
#define NOPS 7

typedef float f32x4 __attribute__((ext_vector_type(4)));

__global__ __launch_bounds__(256) void arth_kernel(
    const float* __restrict__ tv_in,
    const float* __restrict__ td_in,
    const float* __restrict__ op_in,
    const float* __restrict__ if_fin,
    const float* __restrict__ if_val,
    const int* __restrict__ start_pos_p,
    float* __restrict__ out_tv,
    float* __restrict__ out_td,
    float* __restrict__ out_op,
    float* __restrict__ out_iff,
    float* __restrict__ out_iv)
{
    // R5 structure (best measured: 16.60us): block-per-row, tiny LDS,
    // single barrier, copy-loads-first order, plain cached loads,
    // nontemporal stores.
    __shared__ float s_td[SS];
    __shared__ unsigned char s_amax[SS];
    __shared__ unsigned long long sm_op[4];
    __shared__ unsigned long long sm_num[4];

    const int b = blockIdx.x;
    const int t = threadIdx.x;
    const size_t rbase = (size_t)b * SS;
    const size_t obase = (size_t)b * (SS * NOPS);

    // Block-uniform scalars (s_load, overlapped with everything below).
    const int start_pos = *start_pos_p;
    const float fin_f = if_fin[b];
    const float iv0 = if_val[b];

    const f32x4* in4 = (const f32x4*)(op_in + obase);
    f32x4* o4 = (f32x4*)(out_op + obase);

    // ---- Issue ALL global loads back-to-back. ----
    // Copy path first (R8 showed reordering these behind the scalars -3.4us).
    f32x4 v0 = in4[t];
    f32x4 v1;
    if (t < 192) v1 = in4[256 + t];
    // Argmax path: thread t's 7 contiguous floats. Same 1792B wave window as
    // the copy loads -> L1-hot (dual-read ~free: R3 16.73 vs R5 16.60).
    const float* p = op_in + obase + (size_t)t * NOPS;
    const float a0 = p[0], a1 = p[1], a2 = p[2], a3 = p[3];
    const float a4 = p[4], a5 = p[5], a6 = p[6];
    const float tvv = tv_in[rbase + t];
    const float tdv = td_in[rbase + t];

    // Per-position argmax in registers (first-max-lowest-index = jnp.argmax).
    int am = 0; float best = a0;
    if (a1 > best) { best = a1; am = 1; }
    if (a2 > best) { best = a2; am = 2; }
    if (a3 > best) { best = a3; am = 3; }
    if (a4 > best) { best = a4; am = 4; }
    if (a5 > best) { best = a5; am = 5; }
    if (a6 > best) { best = a6; am = 6; }

    s_td[t] = tdv;
    s_amax[t] = (unsigned char)am;

    const bool validtok = (t >= start_pos) && (tvv > 0.5f);
    const bool is_num = validtok && (am == 0);
    const bool is_op = validtok && (am != 0);

    unsigned long long mo = __ballot(is_op);
    unsigned long long mn = __ballot(is_num);
    if ((t & 63) == 0) {
        sm_op[t >> 6] = mo;
        sm_num[t >> 6] = mn;
    }

    // Streaming copy stores (nt stores proven +0.7us in R3/R4 A/B),
    // issued before the barrier, decoupled from the logic path.
    __builtin_nontemporal_store(v0, &o4[t]);
    if (t < 192) __builtin_nontemporal_store(v1, &o4[256 + t]);

    __syncthreads();   // the ONLY barrier: publishes s_td/s_amax/masks

    // All threads scan the 8 mask words (wave-uniform, broadcast LDS reads).
    unsigned long long w_op0 = sm_op[0], w_op1 = sm_op[1], w_op2 = sm_op[2], w_op3 = sm_op[3];
    unsigned long long w_nm[4] = { sm_num[0], sm_num[1], sm_num[2], sm_num[3] };

    // First valid op token j (or -1).
    int j = -1;
    if (w_op0)      j = __builtin_ctzll(w_op0);
    else if (w_op1) j = 64 + __builtin_ctzll(w_op1);
    else if (w_op2) j = 128 + __builtin_ctzll(w_op2);
    else if (w_op3) j = 192 + __builtin_ctzll(w_op3);

    // Top-two push indices strictly below j (or below S if no op).
    int i0 = -1, i1 = -1;
    #pragma unroll
    for (int ww = 3; ww >= 0; --ww) {
        if (i1 >= 0) continue;
        unsigned long long m = w_nm[ww];
        if (j >= 0) {
            int jw = j - ww * 64;
            if (jw <= 0) m = 0ull;
            else if (jw < 64) m &= ((1ull << jw) - 1ull);
        }
        while (m && i1 < 0) {
            int bit = 63 - __builtin_clzll(m);
            if (i0 < 0) i0 = ww * 64 + bit;
            else        i1 = ww * 64 + bit;
            m &= ~(1ull << bit);
        }
    }

    const bool finished = fin_f > 0.5f;
    const bool valid0 = iv0 > 0.5f;

    float otv = tvv, otd = tdv;
    float iff, ivout;
    if (finished) {
        iff = 1.0f;
        ivout = iv0;
    } else if (!valid0) {
        iff = 0.0f;
        ivout = 0.0f;
    } else if (j < 0) {
        ivout = 1.0f;
        iff = (i0 >= 0 && i1 < 0) ? 1.0f : 0.0f;
    } else if (i1 >= 0) {
        float h0 = s_td[i0];   // broadcast read
        float h1 = s_td[i1];   // broadcast read
        int op = s_amax[j];    // broadcast read
        float res;
        switch (op) {
            case 2: res = h1 + h0; break;
            case 3: res = h1 - h0; break;
            case 4: res = h1 * h0; break;
            case 5: res = h1 / (h0 + 1e-7f); break;
            case 6: res = powf(fmaxf(h1, 1e-7f), h0); break;
            default: res = 0.0f; break;   // op index 1 -> zero
        }
        if (t == i0) otd = res;
        if (t == i1 || t == j) otv = 0.0f;
        ivout = 1.0f;
        iff = 0.0f;
    } else {
        ivout = 0.0f;
        iff = 0.0f;
    }

    // Streaming writeback straight from registers.
    __builtin_nontemporal_store(otv, &out_tv[rbase + t]);
    __builtin_nontemporal_store(otd, &out_td[rbase + t]);
    if (t == 0) {
        out_iff[b] = iff;
        out_iv[b] = ivout;
    }
}

extern "C" void kernel_launch(void* const* d_in, const int* in_sizes, int n_in,
                              void* d_out, int out_size, void* d_ws, size_t ws_size,
                              hipStream_t stream) {
    const float* tv_in = (const float*)d_in[0];   // trans_valid (B,S)
    const float* td_in = (const float*)d_in[1];   // trans_dense (B,S)
    const float* op_in = (const float*)d_in[2];   // trans_op (B,S,7)
    const float* if_fin = (const float*)d_in[3];  // if_finished (B,)
    const float* if_val = (const float*)d_in[4];  // if_valid (B,)
    const int* start_pos = (const int*)d_in[5];   // scalar

    float* out = (float*)d_out;
    float* out_tv = out;                                    // B*S
    float* out_td = out + (size_t)BB * SS;                  // B*S
    float* out_op = out + (size_t)2 * BB * SS;              // B*S*7
    float* out_iff = out + (size_t)9 * BB * SS;             // B
    float* out_iv = out + (size_t)9 * BB * SS + BB;         // B

    arth_kernel<<<BB, SS, 0, stream>>>(tv_in, td_in, op_in, if_fin, if_val,
                                       start_pos, out_tv, out_td, out_op,
                                       out_iff, out_iv);
}